// Round 6
// baseline (246.196 us; speedup 1.0000x reference)
//
#include <hip/hip_runtime.h>

using u16 = unsigned short;
using u32 = unsigned int;
using u64 = unsigned long long;

typedef _Float16 half8 __attribute__((ext_vector_type(8)));
typedef float  f32x4 __attribute__((ext_vector_type(4)));
typedef u32    u32x4 __attribute__((ext_vector_type(4)));
typedef u32    u32x2 __attribute__((ext_vector_type(2)));

#define T_STEPS 24
#define NB 4096
#define NF 1024
#define NH 256
#define NCLS 10

// split f32 -> hi + 2^-12*lo (lo stored pre-scaled); per-term err ~2^-23|w|
static __device__ __forceinline__ void f16split(float w, u16& hi, u16& lo) {
  _Float16 h = (_Float16)w;
  float hf = (float)h;
  if (__builtin_fabsf(hf) < 6.103515625e-05f) { h = (_Float16)0.0f; hf = 0.0f; }
  float r = __fmul_rn(__fsub_rn(w, hf), 4096.0f);   // exact residual * 2^12
  _Float16 l = (_Float16)r;
  hi = __builtin_bit_cast(u16, h);
  lo = __builtin_bit_cast(u16, l);
}

// ---------------------------------------------------------------------------
// Prep: W1/W2/W3 -> f16 planes INTERLEAVED per 64-k block: row n holds
// [hi(k 0..63) | lo(k 0..63) | hi(k 64..127) | lo(...)...] so consecutive
// 32-u16 sub-chunks in the GEMM walk hi0|hi1|lo0|lo1 of the SAME spike bits.
// ---------------------------------------------------------------------------
__global__ __launch_bounds__(256) void k_prep(const float* __restrict__ W1,
                                              const float* __restrict__ W2,
                                              const float* __restrict__ W3,
                                              u16* __restrict__ W1hl,
                                              u16* __restrict__ W2hl,
                                              u16* __restrict__ W3hl) {
  int blk = blockIdx.x, tid = threadIdx.x;
  const float* src; u16* dst; int K; int g;
  if (blk < 1024)      { src = W1; dst = W1hl; K = 1024; g = blk * 256 + tid; }
  else if (blk < 1280) { src = W2; dst = W2hl; K = 256;  g = (blk - 1024) * 256 + tid; }
  else                 { src = W3; dst = W3hl; K = 256;  g = (blk - 1280) * 256 + tid; }
  int n = g / K, k = g - n * K;
  u16 hi, lo;
  f16split(src[g], hi, lo);
  int p = k >> 6, j = k & 63;
  u16* d = dst + (size_t)n * 2 * K + p * 128 + j;
  d[0] = hi;
  d[64] = lo;
}

// ---------------------------------------------------------------------------
// One Linear+LIF phase, T3+T4 schedule. 8 waves as 2m x 4n (wave tile
// 48m x 64n, acc[3][4]). K is walked in 32-u16 sub-chunks (one MFMA k-step,
// 12 MFMAs each): group g of 4 sub-chunks = {hi0, hi1, lo0, lo1} of spike
// words (2g, 2g+1); lo fragments derived in-register via *2^-12 (exact).
// Staging: ring of 4 x 16 KB slots, depth-3 prefetch via global_load_lds
// width-16, counted s_waitcnt vmcnt(4/2/0) (own stage) + raw s_barrier
// (join => all stages for slot s landed; all MFMAs s-1 retired => slot
// (s+3)&3 reusable). No full vmcnt drain inside the loop. T5 setprio
// around each MFMA cluster. Fused register LIF unchanged.
// ---------------------------------------------------------------------------
template <int NSC, int ASTRIDE>   // NSC = # 32-u16 sub-chunks (K'/32)
__device__ __forceinline__ void mega_phase(u16* __restrict__ Bs,
                                           const u32* __restrict__ alds,
                                           const u16* __restrict__ wsrc,
                                           u32* __restrict__ zdst,
                                           float scale,
                                           int wid, int lane, int wm, int wn) {
  constexpr int KTOT = NSC * 32;   // u16 per weight row
  constexpr int NG   = NSC / 4;    // groups of 4 sub-chunks

  const int q   = lane >> 4;
  const int bsh = q * 8;

  // staging: wave wid covers rows [wid*32, wid*32+32), 2 loads x 16 rows.
  // lane l -> row (l>>2), 16B-unit (l&3); LDS dest linear (no swizzle:
  // 64-B rows alias banks minimally for the b128 reads below).
  const u16* gs = wsrc + (size_t)(wid * 32 + (lane >> 2)) * KTOT + (lane & 3) * 8;
  const int sdst = wid * 1024;     // u16 offset of wave region within a slot

  auto stage = [&](int s) {
    const int slot = s & 3;
    const u16* g = gs + s * 32;
    #pragma unroll
    for (int r = 0; r < 2; ++r)
      __builtin_amdgcn_global_load_lds(
          (const __attribute__((address_space(1))) u32*)(g + (size_t)r * 16 * KTOT),
          (__attribute__((address_space(3))) u32*)&Bs[slot * 8192 + sdst + r * 512],
          16, 0, 0);
  };

  auto waitv = [&](int n) {   // literal n after unroll -> single asm survives
    if (n == 4)      asm volatile("s_waitcnt vmcnt(4)" ::: "memory");
    else if (n == 2) asm volatile("s_waitcnt vmcnt(2)" ::: "memory");
    else             asm volatile("s_waitcnt vmcnt(0)" ::: "memory");
  };

  // B read base: row = wn*64 + ns*16 + (lane&15), k-unit q -> u16 offset
  const int bru = (wn * 64 + (lane & 15)) * 32 + q * 8;

  int arow[3];
  #pragma unroll
  for (int ms = 0; ms < 3; ++ms)
    arow[ms] = (wm * 48 + ms * 16 + (lane & 15)) * ASTRIDE;

  auto expand = [&](u32 word) -> half8 {
    u32 by = (word >> bsh) & 0xFFu;
    u32 sp = by * 0x8001u;
    u32x4 d;
    d.x = (sp & 0x10001u) * 0x3C00u;
    d.y = ((sp >> 2) & 0x10001u) * 0x3C00u;
    d.z = ((sp >> 4) & 0x10001u) * 0x3C00u;
    d.w = ((sp >> 6) & 0x10001u) * 0x3C00u;
    return __builtin_bit_cast(half8, d);
  };

  const _Float16 scl = (_Float16)2.44140625e-4f;   // 2^-12, exact in f16
  const half8 sc8 = {scl, scl, scl, scl, scl, scl, scl, scl};

  f32x4 acc[3][4];
  #pragma unroll
  for (int ms = 0; ms < 3; ++ms)
    #pragma unroll
    for (int ns = 0; ns < 4; ++ns)
      #pragma unroll
      for (int i = 0; i < 4; ++i) acc[ms][ns][i] = 0.0f;

  half8 afr[3][2];

  // one sub-chunk: wait own stage(s) -> barrier (all stages landed; slot
  // s-1 reads all consumed) -> fence -> prefetch s+3 -> A work -> B reads
  // -> MFMA cluster. j, wcnt, dostage are literals at every call site.
  auto body = [&](int s, int j, int wcnt, bool dostage) {
    waitv(wcnt);
    __builtin_amdgcn_s_barrier();
    asm volatile("" ::: "memory");   // pin ds_reads below the barrier
    if (dostage) stage(s + 3);
    if (j == 0) {
      #pragma unroll
      for (int ms = 0; ms < 3; ++ms) {
        u32x2 bw = *(const u32x2*)(alds + arow[ms] + (s >> 2) * 2);
        afr[ms][0] = expand(bw.x);
        afr[ms][1] = expand(bw.y);
      }
    } else if (j == 2) {
      #pragma unroll
      for (int ms = 0; ms < 3; ++ms) {
        afr[ms][0] = afr[ms][0] * sc8;
        afr[ms][1] = afr[ms][1] * sc8;
      }
    }
    const int sel  = j & 1;
    const int slot = s & 3;
    half8 bfr[4];
    #pragma unroll
    for (int ns = 0; ns < 4; ++ns)
      bfr[ns] = *(const half8*)&Bs[slot * 8192 + bru + ns * 512];
    __builtin_amdgcn_s_setprio(1);
    #pragma unroll
    for (int ns = 0; ns < 4; ++ns)
      #pragma unroll
      for (int ms = 0; ms < 3; ++ms)
        acc[ms][ns] = __builtin_amdgcn_mfma_f32_16x16x32_f16(afr[ms][sel], bfr[ns],
                                                             acc[ms][ns], 0, 0, 0);
    __builtin_amdgcn_s_setprio(0);
  };

  stage(0); stage(1); stage(2);   // depth-3 prologue (6 loads in flight)

  #pragma unroll 2
  for (int g = 0; g < NG - 1; ++g) {
    body(4 * g + 0, 0, 4, true);
    body(4 * g + 1, 1, 4, true);
    body(4 * g + 2, 2, 4, true);
    body(4 * g + 3, 3, 4, true);
  }
  {                                // peeled last group: drain the ring
    const int g = NG - 1;
    body(4 * g + 0, 0, 4, true);
    body(4 * g + 1, 1, 4, false);
    body(4 * g + 2, 2, 2, false);
    body(4 * g + 3, 3, 0, false);
  }
  __syncthreads();   // full drain; staging dead -> reg overlay safe

  // ---- fused LIF: 2 rounds of 32 cols; C/D: col=lane&15, row=q*4+i ----
  float* reg = (float*)Bs + wid * 1600;   // 48 x 33-pad f32 per wave (51.2 KB)
  const int c16 = lane & 15;
  const int b2  = lane >> 5, c = lane & 31;

  #pragma unroll
  for (int r = 0; r < 2; ++r) {
    #pragma unroll
    for (int ms = 0; ms < 3; ++ms)
      #pragma unroll
      for (int j = 0; j < 2; ++j)
        #pragma unroll
        for (int i = 0; i < 4; ++i)
          reg[(ms * 16 + q * 4 + i) * 33 + j * 16 + c16] =
              __fmul_rn(scale, acc[ms][2 * r + j][i]);
    // per-wave region: in-wave lgkm ordering suffices (no barrier)
    float v = 0.0f, ii = 0.0f;
    u32 zw = 0;
    #pragma unroll
    for (int t = 0; t < T_STEPS; ++t) {
      float cv = reg[(b2 * 24 + t) * 33 + c];
      float vdec = __fadd_rn(v, __fmul_rn(0.1f, __fsub_rn(ii, v)));
      float idec = __fmul_rn(0.8f, ii);
      bool z = vdec > 0.33f;
      v = z ? 0.0f : vdec;
      ii = __fadd_rn(idec, cv);
      zw |= ((u32)z) << t;
    }
    #pragma unroll
    for (int t = 0; t < T_STEPS; ++t) {
      u64 m = __ballot((zw >> t) & 1u);
      if (c == 0)
        zdst[((wm * 2 + b2) * 24 + t) * 8 + wn * 2 + r] = (u32)(m >> (b2 * 32));
    }
  }
  __syncthreads();   // zdst complete; reg reads done before next phase
}

// ---------------------------------------------------------------------------
// MEGAKERNEL: one block = 4 batches (96 rows, (b,t) order): encoder + all
// three Linear+LIF layers + factored LI readout. Spike bits never leave LDS.
// ---------------------------------------------------------------------------
__global__ __launch_bounds__(512, 4) void k_mega(const float* __restrict__ x,
                                                 const float* __restrict__ fsp,
                                                 const float* __restrict__ esp,
                                                 const u16* __restrict__ W1hl,
                                                 const u16* __restrict__ W2hl,
                                                 const u16* __restrict__ W3hl,
                                                 const float* __restrict__ Wo,
                                                 float* __restrict__ out) {
  __shared__ __align__(16) u16 Bs[4 * 8192];    // 64 KB: 4 ring slots (+ overlays)
  __shared__ u32 zE[96 * 34];                   // 13.1 KB enc bits (stride 34; zB overlay)
  __shared__ u32 zA[96 * 8];                    // 3 KB z1 bits (z3 overlay)

  const int tid  = threadIdx.x;
  const int wid  = tid >> 6;
  const int lane = tid & 63;
  const int wm   = wid & 1;
  const int wn   = wid >> 1;          // 0..3
  const int b0   = blockIdx.x * 4;

  // ---- encoder: wave covers (bb = wid>>1, f in [fbase, fbase+512)) ----
  {
    const int bb = wid >> 1;
    const int fbase = (wid & 1) * 512;
    const float c2 = __fmul_rn(2.0f, fsp[0]);
    float cur[8], v[8];
    #pragma unroll
    for (int j = 0; j < 8; ++j) {
      cur[j] = __fmul_rn(c2, x[(size_t)(b0 + bb) * 1024 + fbase + j * 64 + lane]);
      v[j] = 0.0f;
    }
    #pragma unroll
    for (int t = 0; t < T_STEPS; ++t) {
      #pragma unroll
      for (int j = 0; j < 8; ++j) {
        v[j] = __fadd_rn(v[j], __fmul_rn(0.1f, __fsub_rn(cur[j], v[j])));
        bool s = v[j] > 1.0f;
        if (s) v[j] = 0.0f;
        u64 m = __ballot(s);
        if (lane == 0) {
          int w0 = (bb * 24 + t) * 34 + (fbase >> 5) + 2 * j;
          zE[w0] = (u32)m;
          zE[w0 + 1] = (u32)(m >> 32);
        }
      }
    }
  }
  __syncthreads();

  const float s1 = __fmul_rn(1.2f, __fmul_rn(5.0f, esp[0]));
  mega_phase<64, 34>(Bs, zE, W1hl, zA, s1, wid, lane, wm, wn);
  mega_phase<16, 8>(Bs, zA, W2hl, zE, 1.2f, wid, lane, wm, wn);   // zB = zE region
  mega_phase<16, 8>(Bs, zE, W3hl, zA, 1.2f, wid, lane, wm, wn);   // z3 -> zA region

  // ---- factored LI readout ----
  // alpha_t = 0.9^(23-t) - 0.8^(23-t)  (closed form of the LI double
  // recurrence; powers constant-folded at compile time).
  // s[b][h] = sum_t alpha_t * z3[b,t,h]  (4x256 f32 in dead staging LDS),
  // out[b][cls] = sum_h Wo[cls][h] * s[b][h]  (40 wave-level 256-dots).
  {
    float* s_lds = (float*)Bs;   // 4 KB
    #pragma unroll
    for (int r = 0; r < 2; ++r) {
      const int idx = tid + r * 512;          // 0..1023 = b*256 + h
      const int b = idx >> 8, h = idx & 255;
      const u32* zp = zA + (b * 24) * 8 + (h >> 5);
      const int bit = h & 31;
      float p9 = 1.0f, p8 = 1.0f, s = 0.0f;
      #pragma unroll
      for (int e = 0; e < 24; ++e) {          // t = 23-e
        const float a = __fsub_rn(p9, p8);    // 0.9^e - 0.8^e (folded const)
        const u32 word = zp[(23 - e) * 8];    // broadcast across 32 lanes
        s = __fadd_rn(s, ((word >> bit) & 1u) ? a : 0.0f);
        p9 = __fmul_rn(p9, 0.9f);
        p8 = __fmul_rn(p8, 0.8f);
      }
      s_lds[idx] = s;
    }
    __syncthreads();
    // wave wid computes outputs o = wid*5 .. wid*5+4  (40 = 4 b x 10 cls)
    #pragma unroll
    for (int oi = 0; oi < 5; ++oi) {
      const int o = wid * 5 + oi;
      const int b = o / 10, cls = o - (o / 10) * 10;
      f32x4 sv = *(const f32x4*)&s_lds[b * 256 + lane * 4];
      f32x4 wv = *(const f32x4*)&Wo[(size_t)cls * 256 + lane * 4];
      float d = __fadd_rn(__fadd_rn(__fmul_rn(sv.x, wv.x), __fmul_rn(sv.y, wv.y)),
                          __fadd_rn(__fmul_rn(sv.z, wv.z), __fmul_rn(sv.w, wv.w)));
      #pragma unroll
      for (int off2 = 32; off2 >= 1; off2 >>= 1)
        d = __fadd_rn(d, __shfl_down(d, off2));
      if (lane == 0) out[(size_t)(b0 + b) * NCLS + cls] = d;
    }
  }
}

// ---------------------------------------------------------------------------
extern "C" void kernel_launch(void* const* d_in, const int* in_sizes, int n_in,
                              void* d_out, int out_size, void* d_ws, size_t ws_size,
                              hipStream_t stream) {
  const float* x  = (const float*)d_in[0];
  const float* W1 = (const float*)d_in[1];
  const float* W2 = (const float*)d_in[2];
  const float* W3 = (const float*)d_in[3];
  const float* Wo = (const float*)d_in[4];
  const float* fs = (const float*)d_in[5];
  const float* es = (const float*)d_in[6];

  char* ws = (char*)d_ws;
  const size_t off_w1 = 0;
  const size_t off_w2 = off_w1 + (size_t)NH * 2 * NF * 2;    // 1.0 MB
  const size_t off_w3 = off_w2 + (size_t)NH * 2 * NH * 2;    // 0.25 MB
  const size_t need   = off_w3 + (size_t)NH * 2 * NH * 2;    // 0.25 MB
  if (ws_size < need) return;

  u16* W1hl = (u16*)(ws + off_w1);
  u16* W2hl = (u16*)(ws + off_w2);
  u16* W3hl = (u16*)(ws + off_w3);

  k_prep<<<dim3(1536), dim3(256), 0, stream>>>(W1, W2, W3, W1hl, W2hl, W3hl);
  // encoder + three Linear+LIF layers + factored LI readout in one dispatch
  k_mega<<<dim3(NB / 4), dim3(512), 0, stream>>>(x, fs, es, W1hl, W2hl, W3hl, Wo,
                                                 (float*)d_out);
}